// Round 8
// baseline (217.740 us; speedup 1.0000x reference)
//
#include <hip/hip_runtime.h>
#include <hip/hip_bf16.h>

#define D_MODEL 1024
#define NUM_HEADS 16
#define D_K 64
#define BATCH 2
#define SEQ 2048

typedef __attribute__((ext_vector_type(8))) short bf16x8;
typedef __attribute__((ext_vector_type(4))) float f32x4;

union P16 { int4 i4; ushort u[8]; };
union FU { float f; unsigned int u; };

__device__ __forceinline__ float bf2f(ushort u) {
    union { unsigned int i; float f; } c; c.i = ((unsigned int)u) << 16; return c.f;
}
__device__ __forceinline__ ushort f2bf(float f) {
    union { float f; unsigned int i; } c; c.f = f;
    unsigned int x = c.i;
    return (ushort)((x + 0x7fff + ((x >> 16) & 1)) >> 16);
}
__device__ __forceinline__ unsigned int cvt_pk_bf16(float lo, float hi) {
    unsigned int r;
    asm("v_cvt_pk_bf16_f32 %0, %1, %2" : "=v"(r) : "v"(lo), "v"(hi));
    return r;
}
// async global->LDS, 16B per lane. LDS dest must be wave-uniform base + lane*16
// (our staging indices are tid-linear; the XOR swizzle lives on the SOURCE side).
__device__ __forceinline__ void gll16(const void* g, void* l) {
    __builtin_amdgcn_global_load_lds(
        (const __attribute__((address_space(1))) void*)g,
        (__attribute__((address_space(3))) void*)l,
        16, 0, 0);
}

// per-wave inline dtype detect (every wave reads the same 64 values -> uniform)
__device__ __forceinline__ bool wave_detect_f32(const ushort* x) {
    ushort u = x[2 * (threadIdx.x & 63)];
    int e = (u >> 7) & 0xFF;
    unsigned long long bl = __ballot(e >= 100 && e <= 141);
    return __popcll(bl) < 32;
}

// ---------------- fused prep: detect + convert_x + both weight transposes ----------------
__global__ __launch_bounds__(256)
void prep_all(const ushort* __restrict__ x, const void* __restrict__ Wq,
              const void* __restrict__ Wo, ushort* __restrict__ xb,
              ushort* __restrict__ WqT, ushort* __restrict__ WoT,
              int* __restrict__ flag)
{
    const bool f32 = wave_detect_f32(x);
    const int bx = blockIdx.x, tx = threadIdx.x;
    if (bx == 0 && tx == 0) flag[0] = f32 ? 1 : 0;

    if (bx >= 1024) {               // convert x -> bf16 (fp32 inputs only)
        if (!f32) return;
        int i = ((bx - 1024) * 256 + tx) * 8;
        const float* f = (const float*)x + i;
        float4 a = *(const float4*)f, b = *(const float4*)(f + 4);
        P16 r;
        r.u[0] = f2bf(a.x); r.u[1] = f2bf(a.y); r.u[2] = f2bf(a.z); r.u[3] = f2bf(a.w);
        r.u[4] = f2bf(b.x); r.u[5] = f2bf(b.y); r.u[6] = f2bf(b.z); r.u[7] = f2bf(b.w);
        *(int4*)(xb + i) = r.i4;
        return;
    }

    __shared__ ushort t[64][72];
    const int nb = bx & 63, kb = bx >> 6;
    const void* W; ushort* WT; int N, n0;
    if (nb < 48) { W = Wq; WT = WqT; N = 3 * D_MODEL; n0 = nb * 64; }
    else         { W = Wo; WT = WoT; N = D_MODEL;     n0 = (nb - 48) * 64; }
    const int k0 = kb * 64, K = D_MODEL;
    #pragma unroll
    for (int p = 0; p < 16; ++p) {
        int r = p * 4 + (tx >> 6), c = tx & 63;
        float v = f32 ? ((const float*)W)[(size_t)(k0 + r) * N + n0 + c]
                      : bf2f(((const ushort*)W)[(size_t)(k0 + r) * N + n0 + c]);
        t[r][c] = f2bf(v);
    }
    __syncthreads();
    #pragma unroll
    for (int p = 0; p < 16; ++p) {
        int nn = p * 4 + (tx >> 6), kk = tx & 63;
        WT[(size_t)(n0 + nn) * K + k0 + kk] = t[kk][nn];
    }
}

// ---------------- GEMM 128x128 v4: global_load_lds staging ----------------
template<int MODE>
__global__ __launch_bounds__(256)
void gemm128(const void* __restrict__ Araw, const ushort* __restrict__ Aconv,
             const ushort* __restrict__ WT, const void* __restrict__ bias,
             void* __restrict__ out, int N, int K, const int* __restrict__ flag)
{
    __shared__ ushort As[2][128 * 32];
    __shared__ ushort Bs[2][128 * 32];

    const int f = *flag;
    const ushort* A = (MODE == 1) ? (f ? Aconv : (const ushort*)Araw) : Aconv;

    const int tid = threadIdx.x;
    const int w = tid >> 6, lane = tid & 63;
    const int ln = lane & 15, quad = lane >> 4;
    const int m0 = blockIdx.y * 128, n0 = blockIdx.x * 128;
    const int wm = (w >> 1) * 64, wn = (w & 1) * 64;

    const int s0 = w * 128 + lane, s1 = s0 + 64;
    const int ar0 = s0 >> 2, ak0 = ((s0 & 3) ^ ((ar0 >> 1) & 3)) * 8;
    const int ar1 = s1 >> 2, ak1 = ((s1 & 3) ^ ((ar1 >> 1) & 3)) * 8;
    const size_t aoff0 = (size_t)(m0 + ar0) * K + ak0;
    const size_t aoff1 = (size_t)(m0 + ar1) * K + ak1;
    const size_t boff0 = (size_t)(n0 + ar0) * K + ak0;
    const size_t boff1 = (size_t)(n0 + ar1) * K + ak1;

    const int physc = (quad ^ ((ln >> 1) & 3)) * 8;

    f32x4 acc[4][4] = {};

    const int nk = K >> 5;
    gll16(A + aoff0,  As[0] + s0 * 8);
    gll16(A + aoff1,  As[0] + s1 * 8);
    gll16(WT + boff0, Bs[0] + s0 * 8);
    gll16(WT + boff1, Bs[0] + s1 * 8);
    __syncthreads();

    for (int kt = 0; kt < nk; ++kt) {
        const int cur = kt & 1;
        if (kt + 1 < nk) {
            const int kc = (kt + 1) * 32;
            gll16(A + aoff0 + kc,  As[1 - cur] + s0 * 8);
            gll16(A + aoff1 + kc,  As[1 - cur] + s1 * 8);
            gll16(WT + boff0 + kc, Bs[1 - cur] + s0 * 8);
            gll16(WT + boff1 + kc, Bs[1 - cur] + s1 * 8);
        }

        bf16x8 af[4], bf[4];
        #pragma unroll
        for (int t = 0; t < 4; ++t) {
            af[t] = *(const bf16x8*)(As[cur] + (wm + t * 16 + ln) * 32 + physc);
            bf[t] = *(const bf16x8*)(Bs[cur] + (wn + t * 16 + ln) * 32 + physc);
        }
        #pragma unroll
        for (int mi = 0; mi < 4; ++mi)
            #pragma unroll
            for (int ni = 0; ni < 4; ++ni)
                acc[mi][ni] = __builtin_amdgcn_mfma_f32_16x16x32_bf16(
                    af[mi], bf[ni], acc[mi][ni], 0, 0, 0);
        __syncthreads();   // drains vmcnt(0): buf[1-cur] staged for next iter
    }

    #pragma unroll
    for (int mi = 0; mi < 4; ++mi) {
        #pragma unroll
        for (int ni = 0; ni < 4; ++ni) {
            int col = n0 + wn + ni * 16 + ln;
            float bb = f ? ((const float*)bias)[col] : bf2f(((const ushort*)bias)[col]);
            #pragma unroll
            for (int r = 0; r < 4; ++r) {
                int row = m0 + wm + mi * 16 + quad * 4 + r;
                float v = acc[mi][ni][r] + bb;
                if (MODE == 0 && f) ((float*)out)[(size_t)row * N + col] = v;
                else                ((ushort*)out)[(size_t)row * N + col] = f2bf(v);
            }
        }
    }
}

// ---------------- GEMM 64x128 v2: global_load_lds staging ----------------
template<int MODE>
__global__ __launch_bounds__(256)
void gemm64(const void* __restrict__ Araw, const ushort* __restrict__ Aconv,
            const ushort* __restrict__ WT, const void* __restrict__ bias,
            void* __restrict__ out, int N, int K, const int* __restrict__ flag)
{
    __shared__ ushort As[2][64 * 32];    // 8 KB
    __shared__ ushort Bs[2][128 * 32];   // 16 KB

    const int f = *flag;
    const ushort* A = (MODE == 1) ? (f ? Aconv : (const ushort*)Araw) : Aconv;

    const int tid = threadIdx.x;
    const int w = tid >> 6, lane = tid & 63;
    const int ln = lane & 15, quad = lane >> 4;
    const int m0 = blockIdx.y * 64, n0 = blockIdx.x * 128;
    const int wn = w * 32;

    const int sa = tid;
    const int arow = sa >> 2, akc = ((sa & 3) ^ ((arow >> 1) & 3)) * 8;
    const size_t aoff = (size_t)(m0 + arow) * K + akc;
    const int sb0 = tid, sb1 = tid + 256;
    const int br0 = sb0 >> 2, bk0 = ((sb0 & 3) ^ ((br0 >> 1) & 3)) * 8;
    const int br1 = sb1 >> 2, bk1 = ((sb1 & 3) ^ ((br1 >> 1) & 3)) * 8;
    const size_t boff0 = (size_t)(n0 + br0) * K + bk0;
    const size_t boff1 = (size_t)(n0 + br1) * K + bk1;

    const int physc = (quad ^ ((ln >> 1) & 3)) * 8;

    f32x4 acc[4][2] = {};

    const int nk = K >> 5;
    gll16(A + aoff,   As[0] + sa * 8);
    gll16(WT + boff0, Bs[0] + sb0 * 8);
    gll16(WT + boff1, Bs[0] + sb1 * 8);
    __syncthreads();

    for (int kt = 0; kt < nk; ++kt) {
        const int cur = kt & 1;
        if (kt + 1 < nk) {
            const int kc = (kt + 1) * 32;
            gll16(A + aoff + kc,   As[1 - cur] + sa * 8);
            gll16(WT + boff0 + kc, Bs[1 - cur] + sb0 * 8);
            gll16(WT + boff1 + kc, Bs[1 - cur] + sb1 * 8);
        }

        bf16x8 af[4], bf[2];
        #pragma unroll
        for (int t = 0; t < 4; ++t)
            af[t] = *(const bf16x8*)(As[cur] + (t * 16 + ln) * 32 + physc);
        #pragma unroll
        for (int t = 0; t < 2; ++t)
            bf[t] = *(const bf16x8*)(Bs[cur] + (wn + t * 16 + ln) * 32 + physc);
        #pragma unroll
        for (int mi = 0; mi < 4; ++mi)
            #pragma unroll
            for (int ni = 0; ni < 2; ++ni)
                acc[mi][ni] = __builtin_amdgcn_mfma_f32_16x16x32_bf16(
                    af[mi], bf[ni], acc[mi][ni], 0, 0, 0);
        __syncthreads();   // drains vmcnt(0): buf[1-cur] staged for next iter
    }

    #pragma unroll
    for (int mi = 0; mi < 4; ++mi) {
        #pragma unroll
        for (int ni = 0; ni < 2; ++ni) {
            int col = n0 + wn + ni * 16 + ln;
            float bb = f ? ((const float*)bias)[col] : bf2f(((const ushort*)bias)[col]);
            #pragma unroll
            for (int r = 0; r < 4; ++r) {
                int row = m0 + mi * 16 + quad * 4 + r;
                float v = acc[mi][ni][r] + bb;
                if (MODE == 0 && f) ((float*)out)[(size_t)row * N + col] = v;
                else                ((ushort*)out)[(size_t)row * N + col] = f2bf(v);
            }
        }
    }
}

// ---------------- MFMA flash attention v15: v13 compute + 18KB LDS + split-K ----------------
// v10 showed 1024 blocks at 36.9KB LDS did NOT raise occupancy (stuck 17% = 2
// blocks/CU) -- hypothesis: LDS allocation granularity rounds 36.9KB up so only
// 2 fit. v15: QPs eliminated (Q stages through Ks+Vs, exactly 128x72 combined)
// -> LDS 18432B, and the v10 split-K (each block owns jt = half, half+2, ...)
// doubles the grid to 1024 so the freed residency is used. Per-block work
// halves, total staging unchanged, v13's reg-P + native-exp loop verbatim.
// Partials -> pO/pL; streaming combine kernel (NOT fused gemm64<2>: round 3
// measured that at ~+23us) produces attn_ws aliased onto dead qkv_ws.
__global__ __launch_bounds__(256)
void flash_attn15(const ushort* __restrict__ qkv, float* __restrict__ pO,
                  float* __restrict__ pL)
{
    __shared__ ushort Ks[64][72];
    __shared__ ushort Vs[64][72];   // total 18432 B; Q stages through both

    const int tid  = threadIdx.x;          // 256 thr, 4 waves
    const int wave = tid >> 6, lane = tid & 63;
    const int ln   = lane & 15, quad = lane >> 4;
    const int pg   = wave >> 1, ww = wave & 1;
    const int bh   = blockIdx.x;    // all blocks of a bh land on XCD bh%8
    const int yy   = blockIdx.y;    // (ky, half)
    const int ky   = yy >> 1, half = yy & 1;
    const int k    = (ky < 8) ? ky : 23 - ky;
    const int xx   = 2 * k + pg;
    const int b    = bh >> 4, hh = bh & (NUM_HEADS - 1);
    const int W3   = 3 * D_MODEL;
    const size_t hbase = (size_t)b * SEQ * W3 + hh * D_K;

    const int q0A = 32 * (63 - xx), q0B = 32 * xx;
    const int ntA = 32 - k, ntB = k + 1;     // identical for both pg; ntA >= 17

    const int qrr = tid >> 1, qcol = (tid & 1) * 32;       // Q: 128 rows x 64
    const int ksr = tid >> 2, ksc = (tid & 3) * 16;        // K: 64 rows, 2 int4
    const int vp  = tid & 31, vg = (tid >> 5) * 8;         // V: 8 b32 each

    // V column permutation: key = u*16 + q*4 + rr  ->  col = q*8 + u*4 + rr
    const int vkey = 2 * vp;
    const int vcol = (vkey & 32) + ((vkey >> 2) & 3) * 8 + ((vkey >> 4) & 1) * 4 + (vkey & 3);

    // stage both pairs' Q tiles (128 rows) through Ks (0-63) / Vs (64-127)
    {
        const int qpg = qrr >> 6, qmt = (qrr >> 5) & 1, ql = qrr & 31;
        const int qxx = 2 * k + qpg;
        const int grow = qmt ? (32 * qxx + ql) : (32 * (63 - qxx) + ql);
        const ushort* src = qkv + hbase + (size_t)grow * W3 + qcol;
        ushort* dst = (qrr < 64) ? &Ks[qrr][qcol] : &Vs[qrr - 64][qcol];
        #pragma unroll
        for (int h = 0; h < 4; ++h) {
            P16 v; v.i4 = *(const int4*)(src + h * 8);
            #pragma unroll
            for (int e = 0; e < 8; ++e) v.u[e] = f2bf(bf2f(v.u[e]) * 0.18033688011f);
            *(int4*)(dst + h * 8) = v.i4;
        }
    }
    __syncthreads();
    bf16x8 qf[2][2];
    {
        const ushort (*Qarr)[72] = pg ? Vs : Ks;   // wave-uniform
        #pragma unroll
        for (int mt = 0; mt < 2; ++mt)
            #pragma unroll
            for (int s = 0; s < 2; ++s)
                qf[mt][s] = *(const bf16x8*)(&Qarr[mt * 32 + ww * 16 + ln][s * 32 + quad * 8]);
    }

    f32x4 acc_o[2][4] = {};
    f32x4 acc_l[2] = {};

    bf16x8 ones8;
    #pragma unroll
    for (int e = 0; e < 8; ++e) ones8[e] = (short)0x3F80;   // bf16 1.0

    const ushort* Kbase = qkv + hbase + D_MODEL;
    const ushort* Vbase = qkv + hbase + 2 * D_MODEL;

    int4 kreg[2], vreg[2];
    {
        const int jf = half * 64;
        const ushort* ksrc = Kbase + (size_t)(jf + ksr) * W3 + ksc;
        kreg[0] = *(const int4*)(ksrc);
        kreg[1] = *(const int4*)(ksrc + 8);
        vreg[0] = *(const int4*)(Vbase + (size_t)(jf + 2 * vp)     * W3 + vg);
        vreg[1] = *(const int4*)(Vbase + (size_t)(jf + 2 * vp + 1) * W3 + vg);
    }

    for (int jt = half; jt < ntA; jt += 2) {
        const int j0 = jt * 64;
        const bool doB = (jt < ntB);
        __syncthreads();   // first pass: all qf reads done before K/V overwrite

        *(int4*)(&Ks[ksr][ksc])     = kreg[0];
        *(int4*)(&Ks[ksr][ksc + 8]) = kreg[1];
        {
            P16 v0, v1; v0.i4 = vreg[0]; v1.i4 = vreg[1];
            #pragma unroll
            for (int e = 0; e < 8; ++e) {
                unsigned int pack = (unsigned int)v0.u[e] | ((unsigned int)v1.u[e] << 16);
                *(unsigned int*)(&Vs[vg + e][vcol]) = pack;
            }
        }
        __syncthreads();

        if (jt + 2 < ntA) {
            const int jn = j0 + 128;
            const ushort* ksrc = Kbase + (size_t)(jn + ksr) * W3 + ksc;
            kreg[0] = *(const int4*)(ksrc);
            kreg[1] = *(const int4*)(ksrc + 8);
            vreg[0] = *(const int4*)(Vbase + (size_t)(jn + 2 * vp)     * W3 + vg);
            vreg[1] = *(const int4*)(Vbase + (size_t)(jn + 2 * vp + 1) * W3 + vg);
        }

        // S^T = mfma(K, Q): lane (ln,quad) holds S[qrow=ln][key=j0+t*16+quad*4+r]
        f32x4 sa[2][4];
        #pragma unroll
        for (int t = 0; t < 4; ++t) {
            bf16x8 k0 = *(const bf16x8*)(&Ks[t * 16 + ln][quad * 8]);
            bf16x8 k1 = *(const bf16x8*)(&Ks[t * 16 + ln][32 + quad * 8]);
            {
                f32x4 z = {};
                z = __builtin_amdgcn_mfma_f32_16x16x32_bf16(k0, qf[0][0], z, 0, 0, 0);
                z = __builtin_amdgcn_mfma_f32_16x16x32_bf16(k1, qf[0][1], z, 0, 0, 0);
                sa[0][t] = z;
            }
            if (doB) {
                f32x4 z = {};
                z = __builtin_amdgcn_mfma_f32_16x16x32_bf16(k0, qf[1][0], z, 0, 0, 0);
                z = __builtin_amdgcn_mfma_f32_16x16x32_bf16(k1, qf[1][1], z, 0, 0, 0);
                sa[1][t] = z;
            }
        }

        if (jt == ntA - 1) {
            const int qrow = q0A + ww * 16 + ln;
            #pragma unroll
            for (int t = 0; t < 4; ++t)
                #pragma unroll
                for (int r = 0; r < 4; ++r)
                    if (j0 + t * 16 + quad * 4 + r > qrow) sa[0][t][r] = -1e30f;
        }
        if (doB && jt == ntB - 1) {
            const int qrow = q0B + ww * 16 + ln;
            #pragma unroll
            for (int t = 0; t < 4; ++t)
                #pragma unroll
                for (int r = 0; r < 4; ++r)
                    if (j0 + t * 16 + quad * 4 + r > qrow) sa[1][t][r] = -1e30f;
        }

        // P stays in registers: A-operand slot e of quad q holds key
        // s*32 + (e>>2)*16 + q*4 + (e&3) -- exactly sa[mt][2s+(e>>2)][e&3].
        union PB { unsigned int w[4]; bf16x8 v; };
        PB pa[2][2];
        #pragma unroll
        for (int mt = 0; mt < 2; ++mt) {
            if (mt && !doB) break;
            #pragma unroll
            for (int s = 0; s < 2; ++s) {
                #pragma unroll
                for (int w = 0; w < 4; ++w) {
                    const int t = 2 * s + (w >> 1);
                    const int r0 = (w & 1) * 2;
                    float lo = __builtin_amdgcn_exp2f(sa[mt][t][r0]);
                    float hi = __builtin_amdgcn_exp2f(sa[mt][t][r0 + 1]);
                    pa[mt][s].w[w] = cvt_pk_bf16(lo, hi);
                }
            }
        }

        #pragma unroll
        for (int s = 0; s < 2; ++s) {
            #pragma unroll
            for (int t = 0; t < 4; ++t) {
                bf16x8 vf = *(const bf16x8*)(&Vs[t * 16 + ln][s * 32 + quad * 8]);
                acc_o[0][t] = __builtin_amdgcn_mfma_f32_16x16x32_bf16(pa[0][s].v, vf, acc_o[0][t], 0, 0, 0);
                if (doB)
                    acc_o[1][t] = __builtin_amdgcn_mfma_f32_16x16x32_bf16(pa[1][s].v, vf, acc_o[1][t], 0, 0, 0);
            }
            acc_l[0] = __builtin_amdgcn_mfma_f32_16x16x32_bf16(pa[0][s].v, ones8, acc_l[0], 0, 0, 0);
            if (doB)
                acc_l[1] = __builtin_amdgcn_mfma_f32_16x16x32_bf16(pa[1][s].v, ones8, acc_l[1], 0, 0, 0);
        }
    }

    // write unnormalized partials for this half
    const size_t oH = (size_t)half * BATCH * SEQ * D_MODEL;
    const size_t lH = (size_t)half * BATCH * SEQ * NUM_HEADS;
    #pragma unroll
    for (int mt = 0; mt < 2; ++mt) {
        const int q0 = mt ? q0B : q0A;
        #pragma unroll
        for (int r = 0; r < 4; ++r) {
            int i = q0 + ww * 16 + quad * 4 + r;
            size_t rowoff = ((size_t)(b * SEQ + i)) * D_MODEL + hh * D_K;
            #pragma unroll
            for (int t = 0; t < 4; ++t)
                pO[oH + rowoff + t * 16 + ln] = acc_o[mt][t][r];
            if (ln == 0)
                pL[lH + (size_t)(b * SEQ + i) * NUM_HEADS + hh] = acc_l[mt][r];
        }
    }
}

// ---------------- streaming split-K combine: attn = (O0+O1)/(L0+L1), bf16 ----------------
__global__ __launch_bounds__(256)
void combine_halves(const float* __restrict__ pO, const float* __restrict__ pL,
                    ushort* __restrict__ attn)
{
    constexpr size_t HALF_O = (size_t)BATCH * SEQ * D_MODEL;
    constexpr size_t HALF_L = (size_t)BATCH * SEQ * NUM_HEADS;
    const size_t idx = ((size_t)blockIdx.x * 256 + threadIdx.x) * 8;
    const int row = (int)(idx >> 10);          // D_MODEL = 1024
    const int hh  = (int)((idx >> 6) & 15);
    const float il = 1.0f / (pL[(size_t)row * NUM_HEADS + hh] +
                             pL[HALF_L + (size_t)row * NUM_HEADS + hh]);
    float4 a0 = *(const float4*)(pO + idx);
    float4 a1 = *(const float4*)(pO + idx + 4);
    float4 b0 = *(const float4*)(pO + HALF_O + idx);
    float4 b1 = *(const float4*)(pO + HALF_O + idx + 4);
    P16 r;
    r.u[0] = f2bf((a0.x + b0.x) * il);
    r.u[1] = f2bf((a0.y + b0.y) * il);
    r.u[2] = f2bf((a0.z + b0.z) * il);
    r.u[3] = f2bf((a0.w + b0.w) * il);
    r.u[4] = f2bf((a1.x + b1.x) * il);
    r.u[5] = f2bf((a1.y + b1.y) * il);
    r.u[6] = f2bf((a1.z + b1.z) * il);
    r.u[7] = f2bf((a1.w + b1.w) * il);
    *(int4*)(attn + idx) = r.i4;
}

// ---------------- MFMA flash attention v13 (fallback when ws too small) ----------------
__global__ __launch_bounds__(256)
void flash_attn13(const ushort* __restrict__ qkv, ushort* __restrict__ attn)
{
    __shared__ ushort Ks[64][72];
    __shared__ ushort Vs[64][72];
    __shared__ ushort QPs[128][72];

    const int tid  = threadIdx.x;
    const int wave = tid >> 6, lane = tid & 63;
    const int ln   = lane & 15, quad = lane >> 4;
    const int pg   = wave >> 1, ww = wave & 1;
    const int bh   = blockIdx.x;
    const int ky   = blockIdx.y;
    const int k    = (ky < 8) ? ky : 23 - ky;
    const int xx   = 2 * k + pg;
    const int b    = bh >> 4, hh = bh & (NUM_HEADS - 1);
    const int W3   = 3 * D_MODEL;
    const size_t hbase = (size_t)b * SEQ * W3 + hh * D_K;

    const int q0A = 32 * (63 - xx), q0B = 32 * xx;
    const int ntA = 32 - k, ntB = k + 1;

    const int qrr = tid >> 1, qcol = (tid & 1) * 32;
    const int ksr = tid >> 2, ksc = (tid & 3) * 16;
    const int vp  = tid & 31, vg = (tid >> 5) * 8;

    const int vkey = 2 * vp;
    const int vcol = (vkey & 32) + ((vkey >> 2) & 3) * 8 + ((vkey >> 4) & 1) * 4 + (vkey & 3);

    {
        const int qpg = qrr >> 6, qmt = (qrr >> 5) & 1, ql = qrr & 31;
        const int qxx = 2 * k + qpg;
        const int grow = qmt ? (32 * qxx + ql) : (32 * (63 - qxx) + ql);
        const ushort* src = qkv + hbase + (size_t)grow * W3 + qcol;
        #pragma unroll
        for (int h = 0; h < 4; ++h) {
            P16 v; v.i4 = *(const int4*)(src + h * 8);
            #pragma unroll
            for (int e = 0; e < 8; ++e) v.u[e] = f2bf(bf2f(v.u[e]) * 0.18033688011f);
            *(int4*)(&QPs[qrr][qcol + h * 8]) = v.i4;
        }
    }
    __syncthreads();
    bf16x8 qf[2][2];
    #pragma unroll
    for (int mt = 0; mt < 2; ++mt)
        #pragma unroll
        for (int s = 0; s < 2; ++s)
            qf[mt][s] = *(const bf16x8*)(&QPs[pg * 64 + mt * 32 + ww * 16 + ln][s * 32 + quad * 8]);

    f32x4 acc_o[2][4] = {};
    f32x4 acc_l[2] = {};

    bf16x8 ones8;
    #pragma unroll
    for (int e = 0; e < 8; ++e) ones8[e] = (short)0x3F80;

    const ushort* Kbase = qkv + hbase + D_MODEL;
    const ushort* Vbase = qkv + hbase + 2 * D_MODEL;

    int4 kreg[2], vreg[2];
    {
        const ushort* ksrc = Kbase + (size_t)ksr * W3 + ksc;
        kreg[0] = *(const int4*)(ksrc);
        kreg[1] = *(const int4*)(ksrc + 8);
        vreg[0] = *(const int4*)(Vbase + (size_t)(2 * vp)     * W3 + vg);
        vreg[1] = *(const int4*)(Vbase + (size_t)(2 * vp + 1) * W3 + vg);
    }

    for (int jt = 0; jt < ntA; ++jt) {
        const int j0 = jt * 64;
        const bool doB = (jt < ntB);
        __syncthreads();

        *(int4*)(&Ks[ksr][ksc])     = kreg[0];
        *(int4*)(&Ks[ksr][ksc + 8]) = kreg[1];
        {
            P16 v0, v1; v0.i4 = vreg[0]; v1.i4 = vreg[1];
            #pragma unroll
            for (int e = 0; e < 8; ++e) {
                unsigned int pack = (unsigned int)v0.u[e] | ((unsigned int)v1.u[e] << 16);
                *(unsigned int*)(&Vs[vg + e][vcol]) = pack;
            }
        }
        __syncthreads();

        if (jt + 1 < ntA) {
            const int jn = j0 + 64;
            const ushort* ksrc = Kbase + (size_t)(jn + ksr) * W3 + ksc;
            kreg[0] = *(const int4*)(ksrc);
            kreg[1] = *(const int4*)(ksrc + 8);
            vreg[0] = *(const int4*)(Vbase + (size_t)(jn + 2 * vp)     * W3 + vg);
            vreg[1] = *(const int4*)(Vbase + (size_t)(jn + 2 * vp + 1) * W3 + vg);
        }

        f32x4 sa[2][4];
        #pragma unroll
        for (int t = 0; t < 4; ++t) {
            bf16x8 k0 = *(const bf16x8*)(&Ks[t * 16 + ln][quad * 8]);
            bf16x8 k1 = *(const bf16x8*)(&Ks[t * 16 + ln][32 + quad * 8]);
            {
                f32x4 z = {};
                z = __builtin_amdgcn_mfma_f32_16x16x32_bf16(k0, qf[0][0], z, 0, 0, 0);
                z = __builtin_amdgcn_mfma_f32_16x16x32_bf16(k1, qf[0][1], z, 0, 0, 0);
                sa[0][t] = z;
            }
            if (doB) {
                f32x4 z = {};
                z = __builtin_amdgcn_mfma_f32_16x16x32_bf16(k0, qf[1][0], z, 0, 0, 0);
                z = __builtin_amdgcn_mfma_f32_16x16x32_bf16(k1, qf[1][1], z, 0, 0, 0);
                sa[1][t] = z;
            }
        }

        if (jt == ntA - 1) {
            const int qrow = q0A + ww * 16 + ln;
            #pragma unroll
            for (int t = 0; t < 4; ++t)
                #pragma unroll
                for (int r = 0; r < 4; ++r)
                    if (j0 + t * 16 + quad * 4 + r > qrow) sa[0][t][r] = -1e30f;
        }
        if (doB && jt == ntB - 1) {
            const int qrow = q0B + ww * 16 + ln;
            #pragma unroll
            for (int t = 0; t < 4; ++t)
                #pragma unroll
                for (int r = 0; r < 4; ++r)
                    if (j0 + t * 16 + quad * 4 + r > qrow) sa[1][t][r] = -1e30f;
        }

        union PB { unsigned int w[4]; bf16x8 v; };
        PB pa[2][2];
        #pragma unroll
        for (int mt = 0; mt < 2; ++mt) {
            if (mt && !doB) break;
            #pragma unroll
            for (int s = 0; s < 2; ++s) {
                #pragma unroll
                for (int w = 0; w < 4; ++w) {
                    const int t = 2 * s + (w >> 1);
                    const int r0 = (w & 1) * 2;
                    float lo = __builtin_amdgcn_exp2f(sa[mt][t][r0]);
                    float hi = __builtin_amdgcn_exp2f(sa[mt][t][r0 + 1]);
                    pa[mt][s].w[w] = cvt_pk_bf16(lo, hi);
                }
            }
        }

        #pragma unroll
        for (int s = 0; s < 2; ++s) {
            #pragma unroll
            for (int t = 0; t < 4; ++t) {
                bf16x8 vf = *(const bf16x8*)(&Vs[t * 16 + ln][s * 32 + quad * 8]);
                acc_o[0][t] = __builtin_amdgcn_mfma_f32_16x16x32_bf16(pa[0][s].v, vf, acc_o[0][t], 0, 0, 0);
                if (doB)
                    acc_o[1][t] = __builtin_amdgcn_mfma_f32_16x16x32_bf16(pa[1][s].v, vf, acc_o[1][t], 0, 0, 0);
            }
            acc_l[0] = __builtin_amdgcn_mfma_f32_16x16x32_bf16(pa[0][s].v, ones8, acc_l[0], 0, 0, 0);
            if (doB)
                acc_l[1] = __builtin_amdgcn_mfma_f32_16x16x32_bf16(pa[1][s].v, ones8, acc_l[1], 0, 0, 0);
        }
    }

    #pragma unroll
    for (int mt = 0; mt < 2; ++mt) {
        const int q0 = mt ? q0B : q0A;
        #pragma unroll
        for (int r = 0; r < 4; ++r) {
            float inv = 1.0f / acc_l[mt][r];
            int i = q0 + ww * 16 + quad * 4 + r;
            size_t rowoff = ((size_t)(b * SEQ + i)) * D_MODEL + hh * D_K;
            #pragma unroll
            for (int t = 0; t < 4; ++t)
                attn[rowoff + t * 16 + ln] = f2bf(acc_o[mt][t][r] * inv);
        }
    }
}

extern "C" void kernel_launch(void* const* d_in, const int* in_sizes, int n_in,
                              void* d_out, int out_size, void* d_ws, size_t ws_size,
                              hipStream_t stream)
{
    const void* x     = d_in[0];
    // d_in[1] = int32 tril mask -- causal handled analytically
    const void* w_qkv = d_in[2];
    const void* b_qkv = d_in[3];
    const void* w_out = d_in[4];
    const void* b_out = d_in[5];

    char* ws = (char*)d_ws;
    int*    flag   = (int*)ws;                  size_t off = 256;
    ushort* WqkvT  = (ushort*)(ws + off);       off += (size_t)3 * D_MODEL * D_MODEL * 2;
    ushort* WoutT  = (ushort*)(ws + off);       off += (size_t)D_MODEL * D_MODEL * 2;
    ushort* qkv_ws = (ushort*)(ws + off);       off += (size_t)BATCH * SEQ * 3 * D_MODEL * 2;
    // share region: xb (x-convert, dead after QKV gemm) aliases pO (split-K partials)
    char*   share  = ws + off;
    ushort* xb     = (ushort*)share;
    float*  pO     = (float*)share;
    const size_t pO_bytes = (size_t)2 * BATCH * SEQ * D_MODEL * 4;   // 33.5 MB
    float*  pL     = (float*)(share + pO_bytes);
    const size_t pL_bytes = (size_t)2 * BATCH * SEQ * NUM_HEADS * 4; // 0.5 MB
    const bool use_split = ws_size >= off + pO_bytes + pL_bytes;
    // attn_ws for split path aliases qkv_ws (dead after flash);
    // fallback path aliases xb (dead after QKV gemm), as before.
    ushort* attn_split = qkv_ws;
    ushort* attn_fb    = xb;

    const int M = BATCH * SEQ;          // 4096

    prep_all<<<3072, 256, 0, stream>>>((const ushort*)x, w_qkv, w_out,
                                       xb, WqkvT, WoutT, flag);

    gemm128<1><<<dim3(3 * D_MODEL / 128, M / 128), 256, 0, stream>>>(
        x, xb, WqkvT, b_qkv, qkv_ws, 3 * D_MODEL, D_MODEL, flag);

    if (use_split) {
        dim3 ga(BATCH * NUM_HEADS, 32);   // x = bh (XCD locality), y = (ky, half)
        flash_attn15<<<ga, 256, 0, stream>>>(qkv_ws, pO, pL);
        combine_halves<<<(BATCH * SEQ * D_MODEL) / (256 * 8), 256, 0, stream>>>(
            pO, pL, attn_split);
        gemm64<0><<<dim3(D_MODEL / 128, M / 64), 256, 0, stream>>>(
            attn_split, attn_split, WoutT, b_out, d_out, D_MODEL, D_MODEL, flag);
    } else {
        dim3 ga(BATCH * NUM_HEADS, 16);   // x = bh (XCD locality), y = ky
        flash_attn13<<<ga, 256, 0, stream>>>(qkv_ws, attn_fb);
        gemm64<0><<<dim3(D_MODEL / 128, M / 64), 256, 0, stream>>>(
            attn_fb, attn_fb, WoutT, b_out, d_out, D_MODEL, D_MODEL, flag);
    }
}

// Round 11
// 205.499 us; speedup vs baseline: 1.0596x; 1.0596x over previous
//
#include <hip/hip_runtime.h>
#include <hip/hip_bf16.h>

#define D_MODEL 1024
#define NUM_HEADS 16
#define D_K 64
#define BATCH 2
#define SEQ 2048

typedef __attribute__((ext_vector_type(8))) short bf16x8;
typedef __attribute__((ext_vector_type(4))) float f32x4;

union P16 { int4 i4; ushort u[8]; };
union FU { float f; unsigned int u; };

__device__ __forceinline__ float bf2f(ushort u) {
    union { unsigned int i; float f; } c; c.i = ((unsigned int)u) << 16; return c.f;
}
__device__ __forceinline__ ushort f2bf(float f) {
    union { float f; unsigned int i; } c; c.f = f;
    unsigned int x = c.i;
    return (ushort)((x + 0x7fff + ((x >> 16) & 1)) >> 16);
}
__device__ __forceinline__ unsigned int cvt_pk_bf16(float lo, float hi) {
    unsigned int r;
    asm("v_cvt_pk_bf16_f32 %0, %1, %2" : "=v"(r) : "v"(lo), "v"(hi));
    return r;
}

// per-wave inline dtype detect (every wave reads the same 64 values -> uniform)
__device__ __forceinline__ bool wave_detect_f32(const ushort* x) {
    ushort u = x[2 * (threadIdx.x & 63)];
    int e = (u >> 7) & 0xFF;
    unsigned long long bl = __ballot(e >= 100 && e <= 141);
    return __popcll(bl) < 32;
}

// ---------------- fused prep: detect + convert_x + both weight transposes ----------------
__global__ __launch_bounds__(256)
void prep_all(const ushort* __restrict__ x, const void* __restrict__ Wq,
              const void* __restrict__ Wo, ushort* __restrict__ xb,
              ushort* __restrict__ WqT, ushort* __restrict__ WoT,
              int* __restrict__ flag)
{
    const bool f32 = wave_detect_f32(x);
    const int bx = blockIdx.x, tx = threadIdx.x;
    if (bx == 0 && tx == 0) flag[0] = f32 ? 1 : 0;

    if (bx >= 1024) {               // convert x -> bf16 (fp32 inputs only)
        if (!f32) return;
        int i = ((bx - 1024) * 256 + tx) * 8;
        const float* f = (const float*)x + i;
        float4 a = *(const float4*)f, b = *(const float4*)(f + 4);
        P16 r;
        r.u[0] = f2bf(a.x); r.u[1] = f2bf(a.y); r.u[2] = f2bf(a.z); r.u[3] = f2bf(a.w);
        r.u[4] = f2bf(b.x); r.u[5] = f2bf(b.y); r.u[6] = f2bf(b.z); r.u[7] = f2bf(b.w);
        *(int4*)(xb + i) = r.i4;
        return;
    }

    __shared__ ushort t[64][72];
    const int nb = bx & 63, kb = bx >> 6;
    const void* W; ushort* WT; int N, n0;
    if (nb < 48) { W = Wq; WT = WqT; N = 3 * D_MODEL; n0 = nb * 64; }
    else         { W = Wo; WT = WoT; N = D_MODEL;     n0 = (nb - 48) * 64; }
    const int k0 = kb * 64, K = D_MODEL;
    #pragma unroll
    for (int p = 0; p < 16; ++p) {
        int r = p * 4 + (tx >> 6), c = tx & 63;
        float v = f32 ? ((const float*)W)[(size_t)(k0 + r) * N + n0 + c]
                      : bf2f(((const ushort*)W)[(size_t)(k0 + r) * N + n0 + c]);
        t[r][c] = f2bf(v);
    }
    __syncthreads();
    #pragma unroll
    for (int p = 0; p < 16; ++p) {
        int nn = p * 4 + (tx >> 6), kk = tx & 63;
        WT[(size_t)(n0 + nn) * K + k0 + kk] = t[kk][nn];
    }
}

// ---------------- GEMM 128x128 (reg-staged dbuf; 208.05us-best inner loop) + XCD swizzle ----
// Bijective quadrant swizzle: xcd = lid&7 owns an (8m x 12n) quadrant so each
// XCD L2 re-reads only its own A/B panels (A ~117MB -> ~17MB HBM).
template<int MODE>
__global__ __launch_bounds__(256)
void gemm128(const void* __restrict__ Araw, const ushort* __restrict__ Aconv,
             const ushort* __restrict__ WT, const void* __restrict__ bias,
             void* __restrict__ out, int N, int K, const int* __restrict__ flag)
{
    __shared__ ushort As[2][128 * 32];
    __shared__ ushort Bs[2][128 * 32];

    const int f = *flag;
    const ushort* A = (MODE == 1) ? (f ? Aconv : (const ushort*)Araw) : Aconv;

    const int tid = threadIdx.x;
    const int w = tid >> 6, lane = tid & 63;
    const int ln = lane & 15, quad = lane >> 4;

    const int lid = blockIdx.x;
    const int xcd = lid & 7, idx = lid >> 3;         // idx in 0..95
    const int mb = (xcd >> 1) * 8 + (idx & 7);       // 0..31
    const int nbk = (xcd & 1) * 12 + (idx >> 3);     // 0..23
    const int m0 = mb * 128, n0 = nbk * 128;

    const int wm = (w >> 1) * 64, wn = (w & 1) * 64;

    const int s0 = w * 128 + lane, s1 = s0 + 64;
    const int ar0 = s0 >> 2, ak0 = ((s0 & 3) ^ ((ar0 >> 1) & 3)) * 8;
    const int ar1 = s1 >> 2, ak1 = ((s1 & 3) ^ ((ar1 >> 1) & 3)) * 8;
    const size_t aoff0 = (size_t)(m0 + ar0) * K + ak0;
    const size_t aoff1 = (size_t)(m0 + ar1) * K + ak1;
    const size_t boff0 = (size_t)(n0 + ar0) * K + ak0;
    const size_t boff1 = (size_t)(n0 + ar1) * K + ak1;

    const int physc = (quad ^ ((ln >> 1) & 3)) * 8;

    f32x4 acc[4][4] = {};

    const int nk = K >> 5;
    int4 a0 = *(const int4*)(A + aoff0);
    int4 a1 = *(const int4*)(A + aoff1);
    int4 b0 = *(const int4*)(WT + boff0);
    int4 b1 = *(const int4*)(WT + boff1);
    *(int4*)(As[0] + s0 * 8) = a0;
    *(int4*)(As[0] + s1 * 8) = a1;
    *(int4*)(Bs[0] + s0 * 8) = b0;
    *(int4*)(Bs[0] + s1 * 8) = b1;
    a0 = *(const int4*)(A + aoff0 + 32);
    a1 = *(const int4*)(A + aoff1 + 32);
    b0 = *(const int4*)(WT + boff0 + 32);
    b1 = *(const int4*)(WT + boff1 + 32);
    __syncthreads();

    for (int kt = 0; kt < nk; ++kt) {
        const int cur = kt & 1;
        if (kt + 1 < nk) {
            *(int4*)(As[1 - cur] + s0 * 8) = a0;
            *(int4*)(As[1 - cur] + s1 * 8) = a1;
            *(int4*)(Bs[1 - cur] + s0 * 8) = b0;
            *(int4*)(Bs[1 - cur] + s1 * 8) = b1;
        }
        if (kt + 2 < nk) {
            const int kc = (kt + 2) * 32;
            a0 = *(const int4*)(A + aoff0 + kc);
            a1 = *(const int4*)(A + aoff1 + kc);
            b0 = *(const int4*)(WT + boff0 + kc);
            b1 = *(const int4*)(WT + boff1 + kc);
        }

        bf16x8 af[4], bf[4];
        #pragma unroll
        for (int t = 0; t < 4; ++t) {
            af[t] = *(const bf16x8*)(As[cur] + (wm + t * 16 + ln) * 32 + physc);
            bf[t] = *(const bf16x8*)(Bs[cur] + (wn + t * 16 + ln) * 32 + physc);
        }
        #pragma unroll
        for (int mi = 0; mi < 4; ++mi)
            #pragma unroll
            for (int ni = 0; ni < 4; ++ni)
                acc[mi][ni] = __builtin_amdgcn_mfma_f32_16x16x32_bf16(
                    af[mi], bf[ni], acc[mi][ni], 0, 0, 0);
        __syncthreads();
    }

    #pragma unroll
    for (int mi = 0; mi < 4; ++mi) {
        #pragma unroll
        for (int ni = 0; ni < 4; ++ni) {
            int col = n0 + wn + ni * 16 + ln;
            float bb = f ? ((const float*)bias)[col] : bf2f(((const ushort*)bias)[col]);
            #pragma unroll
            for (int r = 0; r < 4; ++r) {
                int row = m0 + wm + mi * 16 + quad * 4 + r;
                float v = acc[mi][ni][r] + bb;
                if (MODE == 0 && f) ((float*)out)[(size_t)row * N + col] = v;
                else                ((ushort*)out)[(size_t)row * N + col] = f2bf(v);
            }
        }
    }
}

// ---------------- GEMM 64x128 (reg-staged dbuf) + XCD m-chunk swizzle ----------------
// Bijective: xcd owns 8 consecutive m-blocks x all 8 n-blocks (A read ~once).
template<int MODE>
__global__ __launch_bounds__(256)
void gemm64(const void* __restrict__ Araw, const ushort* __restrict__ Aconv,
            const ushort* __restrict__ WT, const void* __restrict__ bias,
            void* __restrict__ out, int N, int K, const int* __restrict__ flag)
{
    __shared__ ushort As[2][64 * 32];    // 8 KB
    __shared__ ushort Bs[2][128 * 32];   // 16 KB

    const int f = *flag;
    const ushort* A = (MODE == 1) ? (f ? Aconv : (const ushort*)Araw) : Aconv;

    const int tid = threadIdx.x;
    const int w = tid >> 6, lane = tid & 63;
    const int ln = lane & 15, quad = lane >> 4;

    const int lid = blockIdx.x;
    const int xcd = lid & 7, idx = lid >> 3;         // idx in 0..63
    const int mb = xcd * 8 + (idx & 7);              // 0..63
    const int nbk = idx >> 3;                        // 0..7
    const int m0 = mb * 64, n0 = nbk * 128;

    const int wn = w * 32;

    const int sa = tid;
    const int arow = sa >> 2, akc = ((sa & 3) ^ ((arow >> 1) & 3)) * 8;
    const size_t aoff = (size_t)(m0 + arow) * K + akc;
    const int sb0 = tid, sb1 = tid + 256;
    const int br0 = sb0 >> 2, bk0 = ((sb0 & 3) ^ ((br0 >> 1) & 3)) * 8;
    const int br1 = sb1 >> 2, bk1 = ((sb1 & 3) ^ ((br1 >> 1) & 3)) * 8;
    const size_t boff0 = (size_t)(n0 + br0) * K + bk0;
    const size_t boff1 = (size_t)(n0 + br1) * K + bk1;

    const int physc = (quad ^ ((ln >> 1) & 3)) * 8;

    f32x4 acc[4][2] = {};

    const int nk = K >> 5;
    int4 a0 = *(const int4*)(A + aoff);
    int4 b0 = *(const int4*)(WT + boff0);
    int4 b1 = *(const int4*)(WT + boff1);
    *(int4*)(As[0] + sa * 8)  = a0;
    *(int4*)(Bs[0] + sb0 * 8) = b0;
    *(int4*)(Bs[0] + sb1 * 8) = b1;
    a0 = *(const int4*)(A + aoff + 32);
    b0 = *(const int4*)(WT + boff0 + 32);
    b1 = *(const int4*)(WT + boff1 + 32);
    __syncthreads();

    for (int kt = 0; kt < nk; ++kt) {
        const int cur = kt & 1;
        if (kt + 1 < nk) {
            *(int4*)(As[1 - cur] + sa * 8)  = a0;
            *(int4*)(Bs[1 - cur] + sb0 * 8) = b0;
            *(int4*)(Bs[1 - cur] + sb1 * 8) = b1;
        }
        if (kt + 2 < nk) {
            const int kc = (kt + 2) * 32;
            a0 = *(const int4*)(A + aoff + kc);
            b0 = *(const int4*)(WT + boff0 + kc);
            b1 = *(const int4*)(WT + boff1 + kc);
        }

        bf16x8 af[4], bf[2];
        #pragma unroll
        for (int t = 0; t < 4; ++t)
            af[t] = *(const bf16x8*)(As[cur] + (t * 16 + ln) * 32 + physc);
        #pragma unroll
        for (int t = 0; t < 2; ++t)
            bf[t] = *(const bf16x8*)(Bs[cur] + (wn + t * 16 + ln) * 32 + physc);
        #pragma unroll
        for (int mi = 0; mi < 4; ++mi)
            #pragma unroll
            for (int ni = 0; ni < 2; ++ni)
                acc[mi][ni] = __builtin_amdgcn_mfma_f32_16x16x32_bf16(
                    af[mi], bf[ni], acc[mi][ni], 0, 0, 0);
        __syncthreads();
    }

    #pragma unroll
    for (int mi = 0; mi < 4; ++mi) {
        #pragma unroll
        for (int ni = 0; ni < 2; ++ni) {
            int col = n0 + wn + ni * 16 + ln;
            float bb = f ? ((const float*)bias)[col] : bf2f(((const ushort*)bias)[col]);
            #pragma unroll
            for (int r = 0; r < 4; ++r) {
                int row = m0 + mi * 16 + quad * 4 + r;
                float v = acc[mi][ni][r] + bb;
                if (MODE == 0 && f) ((float*)out)[(size_t)row * N + col] = v;
                else                ((ushort*)out)[(size_t)row * N + col] = f2bf(v);
            }
        }
    }
}

// ---------------- MFMA flash attention v13 (verbatim 61.1us best; NO setprio) ----------------
__global__ __launch_bounds__(256)
void flash_attn13(const ushort* __restrict__ qkv, ushort* __restrict__ attn)
{
    __shared__ ushort Ks[64][72];
    __shared__ ushort Vs[64][72];
    __shared__ ushort QPs[128][72];  // Q staging only (dead after qf load)

    const int tid  = threadIdx.x;          // 256 thr, 4 waves
    const int wave = tid >> 6, lane = tid & 63;
    const int ln   = lane & 15, quad = lane >> 4;
    const int pg   = wave >> 1, ww = wave & 1;
    const int bh   = blockIdx.x;    // all blocks of a bh land on XCD bh%8
    const int ky   = blockIdx.y;
    const int k    = (ky < 8) ? ky : 23 - ky;
    const int xx   = 2 * k + pg;
    const int b    = bh >> 4, hh = bh & (NUM_HEADS - 1);
    const int W3   = 3 * D_MODEL;
    const size_t hbase = (size_t)b * SEQ * W3 + hh * D_K;

    const int q0A = 32 * (63 - xx), q0B = 32 * xx;
    const int ntA = 32 - k, ntB = k + 1;     // identical for both pg

    const int qrr = tid >> 1, qcol = (tid & 1) * 32;       // Q: 128 rows x 64
    const int ksr = tid >> 2, ksc = (tid & 3) * 16;        // K: 64 rows, 2 int4
    const int vp  = tid & 31, vg = (tid >> 5) * 8;         // V: 8 b32 each

    // V column permutation: key = u*16 + q*4 + rr  ->  col = q*8 + u*4 + rr
    const int vkey = 2 * vp;
    const int vcol = (vkey & 32) + ((vkey >> 2) & 3) * 8 + ((vkey >> 4) & 1) * 4 + (vkey & 3);

    // stage both pairs' Q tiles (128 rows), scaled by 0.125*log2(e)
    {
        const int qpg = qrr >> 6, qmt = (qrr >> 5) & 1, ql = qrr & 31;
        const int qxx = 2 * k + qpg;
        const int grow = qmt ? (32 * qxx + ql) : (32 * (63 - qxx) + ql);
        const ushort* src = qkv + hbase + (size_t)grow * W3 + qcol;
        #pragma unroll
        for (int h = 0; h < 4; ++h) {
            P16 v; v.i4 = *(const int4*)(src + h * 8);
            #pragma unroll
            for (int e = 0; e < 8; ++e) v.u[e] = f2bf(bf2f(v.u[e]) * 0.18033688011f);
            *(int4*)(&QPs[qrr][qcol + h * 8]) = v.i4;
        }
    }
    __syncthreads();
    bf16x8 qf[2][2];
    #pragma unroll
    for (int mt = 0; mt < 2; ++mt)
        #pragma unroll
        for (int s = 0; s < 2; ++s)
            qf[mt][s] = *(const bf16x8*)(&QPs[pg * 64 + mt * 32 + ww * 16 + ln][s * 32 + quad * 8]);

    f32x4 acc_o[2][4] = {};
    f32x4 acc_l[2] = {};

    bf16x8 ones8;
    #pragma unroll
    for (int e = 0; e < 8; ++e) ones8[e] = (short)0x3F80;   // bf16 1.0

    const ushort* Kbase = qkv + hbase + D_MODEL;
    const ushort* Vbase = qkv + hbase + 2 * D_MODEL;

    int4 kreg[2], vreg[2];
    {
        const ushort* ksrc = Kbase + (size_t)ksr * W3 + ksc;
        kreg[0] = *(const int4*)(ksrc);
        kreg[1] = *(const int4*)(ksrc + 8);
        vreg[0] = *(const int4*)(Vbase + (size_t)(2 * vp)     * W3 + vg);
        vreg[1] = *(const int4*)(Vbase + (size_t)(2 * vp + 1) * W3 + vg);
    }

    for (int jt = 0; jt < ntA; ++jt) {
        const int j0 = jt * 64;
        const bool doB = (jt < ntB);
        __syncthreads();

        *(int4*)(&Ks[ksr][ksc])     = kreg[0];
        *(int4*)(&Ks[ksr][ksc + 8]) = kreg[1];
        {
            P16 v0, v1; v0.i4 = vreg[0]; v1.i4 = vreg[1];
            #pragma unroll
            for (int e = 0; e < 8; ++e) {
                unsigned int pack = (unsigned int)v0.u[e] | ((unsigned int)v1.u[e] << 16);
                *(unsigned int*)(&Vs[vg + e][vcol]) = pack;
            }
        }
        __syncthreads();

        if (jt + 1 < ntA) {
            const int jn = j0 + 64;
            const ushort* ksrc = Kbase + (size_t)(jn + ksr) * W3 + ksc;
            kreg[0] = *(const int4*)(ksrc);
            kreg[1] = *(const int4*)(ksrc + 8);
            vreg[0] = *(const int4*)(Vbase + (size_t)(jn + 2 * vp)     * W3 + vg);
            vreg[1] = *(const int4*)(Vbase + (size_t)(jn + 2 * vp + 1) * W3 + vg);
        }

        // S^T = mfma(K, Q): lane (ln,quad) holds S[qrow=ln][key=j0+t*16+quad*4+r]
        f32x4 sa[2][4];
        #pragma unroll
        for (int t = 0; t < 4; ++t) {
            bf16x8 k0 = *(const bf16x8*)(&Ks[t * 16 + ln][quad * 8]);
            bf16x8 k1 = *(const bf16x8*)(&Ks[t * 16 + ln][32 + quad * 8]);
            {
                f32x4 z = {};
                z = __builtin_amdgcn_mfma_f32_16x16x32_bf16(k0, qf[0][0], z, 0, 0, 0);
                z = __builtin_amdgcn_mfma_f32_16x16x32_bf16(k1, qf[0][1], z, 0, 0, 0);
                sa[0][t] = z;
            }
            if (doB) {
                f32x4 z = {};
                z = __builtin_amdgcn_mfma_f32_16x16x32_bf16(k0, qf[1][0], z, 0, 0, 0);
                z = __builtin_amdgcn_mfma_f32_16x16x32_bf16(k1, qf[1][1], z, 0, 0, 0);
                sa[1][t] = z;
            }
        }

        if (jt == ntA - 1) {
            const int qrow = q0A + ww * 16 + ln;
            #pragma unroll
            for (int t = 0; t < 4; ++t)
                #pragma unroll
                for (int r = 0; r < 4; ++r)
                    if (j0 + t * 16 + quad * 4 + r > qrow) sa[0][t][r] = -1e30f;
        }
        if (doB && jt == ntB - 1) {
            const int qrow = q0B + ww * 16 + ln;
            #pragma unroll
            for (int t = 0; t < 4; ++t)
                #pragma unroll
                for (int r = 0; r < 4; ++r)
                    if (j0 + t * 16 + quad * 4 + r > qrow) sa[1][t][r] = -1e30f;
        }

        // P stays in registers: A-operand slot e of quad q holds key
        // s*32 + (e>>2)*16 + q*4 + (e&3) -- exactly sa[mt][2s+(e>>2)][e&3].
        union PB { unsigned int w[4]; bf16x8 v; };
        PB pa[2][2];
        #pragma unroll
        for (int mt = 0; mt < 2; ++mt) {
            if (mt && !doB) break;
            #pragma unroll
            for (int s = 0; s < 2; ++s) {
                #pragma unroll
                for (int w = 0; w < 4; ++w) {
                    const int t = 2 * s + (w >> 1);
                    const int r0 = (w & 1) * 2;
                    float lo = __builtin_amdgcn_exp2f(sa[mt][t][r0]);
                    float hi = __builtin_amdgcn_exp2f(sa[mt][t][r0 + 1]);
                    pa[mt][s].w[w] = cvt_pk_bf16(lo, hi);
                }
            }
        }

        #pragma unroll
        for (int s = 0; s < 2; ++s) {
            #pragma unroll
            for (int t = 0; t < 4; ++t) {
                bf16x8 vf = *(const bf16x8*)(&Vs[t * 16 + ln][s * 32 + quad * 8]);
                acc_o[0][t] = __builtin_amdgcn_mfma_f32_16x16x32_bf16(pa[0][s].v, vf, acc_o[0][t], 0, 0, 0);
                if (doB)
                    acc_o[1][t] = __builtin_amdgcn_mfma_f32_16x16x32_bf16(pa[1][s].v, vf, acc_o[1][t], 0, 0, 0);
            }
            acc_l[0] = __builtin_amdgcn_mfma_f32_16x16x32_bf16(pa[0][s].v, ones8, acc_l[0], 0, 0, 0);
            if (doB)
                acc_l[1] = __builtin_amdgcn_mfma_f32_16x16x32_bf16(pa[1][s].v, ones8, acc_l[1], 0, 0, 0);
        }
    }

    #pragma unroll
    for (int mt = 0; mt < 2; ++mt) {
        const int q0 = mt ? q0B : q0A;
        #pragma unroll
        for (int r = 0; r < 4; ++r) {
            float inv = 1.0f / acc_l[mt][r];
            int i = q0 + ww * 16 + quad * 4 + r;
            size_t rowoff = ((size_t)(b * SEQ + i)) * D_MODEL + hh * D_K;
            #pragma unroll
            for (int t = 0; t < 4; ++t)
                attn[rowoff + t * 16 + ln] = f2bf(acc_o[mt][t][r] * inv);
        }
    }
}

extern "C" void kernel_launch(void* const* d_in, const int* in_sizes, int n_in,
                              void* d_out, int out_size, void* d_ws, size_t ws_size,
                              hipStream_t stream)
{
    const void* x     = d_in[0];
    // d_in[1] = int32 tril mask -- causal handled analytically
    const void* w_qkv = d_in[2];
    const void* b_qkv = d_in[3];
    const void* w_out = d_in[4];
    const void* b_out = d_in[5];

    char* ws = (char*)d_ws;
    int*    flag   = (int*)ws;                  size_t off = 256;
    ushort* WqkvT  = (ushort*)(ws + off);       off += (size_t)3 * D_MODEL * D_MODEL * 2;
    ushort* WoutT  = (ushort*)(ws + off);       off += (size_t)D_MODEL * D_MODEL * 2;
    ushort* qkv_ws = (ushort*)(ws + off);       off += (size_t)BATCH * SEQ * 3 * D_MODEL * 2;
    ushort* xb     = (ushort*)(ws + off);       // aliases attn_ws: xb dead after QKV gemm
    ushort* attn_ws = xb;

    const int M = BATCH * SEQ;          // 4096

    prep_all<<<3072, 256, 0, stream>>>((const ushort*)x, w_qkv, w_out,
                                       xb, WqkvT, WoutT, flag);

    gemm128<1><<<(3 * D_MODEL / 128) * (M / 128), 256, 0, stream>>>(
        x, xb, WqkvT, b_qkv, qkv_ws, 3 * D_MODEL, D_MODEL, flag);

    dim3 ga(BATCH * NUM_HEADS, 16);   // x = bh (XCD locality), y = ky
    flash_attn13<<<ga, 256, 0, stream>>>(qkv_ws, attn_ws);

    gemm64<0><<<(D_MODEL / 128) * (M / 64), 256, 0, stream>>>(
        attn_ws, attn_ws, WoutT, b_out, d_out, D_MODEL, D_MODEL, flag);
}